// Round 12
// baseline (778.014 us; speedup 1.0000x reference)
//
#include <hip/hip_runtime.h>
#include <cstdint>
#include <cstddef>
#include <math.h>

// ---------------------------------------------------------------------------
// SturtGAT round 20: fused GEMM-L0 + SEGMENTED count.
// R19 measured the fusion: 760us total, fused dispatch 130us with MfmaUtil
// 5.8% -- the count path's memory-side atomic serialization (~114us) is the
// critical path; GEMM hides inside it. Fix: R15's segmented counters (8
// segments -> 8x more atomic lines, ~2 RMW/counter-line instead of 16)
// applied INSIDE the fused kernel. R15 standalone was net-neutral because
// its +15us overhead offset the win; under fusion the win is wall-time.
// segcnt aliases stB after posb (both dead post-fill3).
// ---------------------------------------------------------------------------

typedef __attribute__((ext_vector_type(8))) short short8;   // 8 bf16 (4 VGPRs)
typedef __attribute__((ext_vector_type(4))) float f32x4;    // 4 fp32 acc
typedef __attribute__((ext_vector_type(2))) float f32x2;    // packed fma pair

struct P3f { const float* p[3]; };
struct P3c { const int* p[3]; };

#define SSEG 8
#define SEGSH 17   // 131072 edges per segment; E=800000 -> 7 segments used

__device__ __forceinline__ float leakyf(float x) { return x > 0.f ? x : 0.2f * x; }
__device__ __forceinline__ float eluf(float x)   { return x > 0.f ? x : expm1f(x); }

__device__ __forceinline__ unsigned short bf16r(float x) {  // RNE fp32->bf16
  unsigned int u = __float_as_uint(x);
  u += 0x7fffu + ((u >> 16) & 1u);
  return (unsigned short)(u >> 16);
}
__device__ __forceinline__ float bflo(unsigned int u) { return __uint_as_float(u << 16); }
__device__ __forceinline__ float bfhi(unsigned int u) { return __uint_as_float(u & 0xffff0000u); }

// unpack 8 bf16 (uint4), packed-fma into a[0..3] (f32x2 each) with scalar xx
__device__ __forceinline__ void bf8_fma2(uint4 q, float xx, f32x2* a) {
  f32x2 v0 = {bflo(q.x), bfhi(q.x)};
  f32x2 v1 = {bflo(q.y), bfhi(q.y)};
  f32x2 v2 = {bflo(q.z), bfhi(q.z)};
  f32x2 v3 = {bflo(q.w), bfhi(q.w)};
  a[0] += xx * v0;
  a[1] += xx * v1;
  a[2] += xx * v2;
  a[3] += xx * v3;
}

// ---------------- utility ----------------
__global__ __launch_bounds__(256) void zero_int_kernel(int* p, int n) {
  int i = blockIdx.x * blockDim.x + threadIdx.x;
  if (i < n) p[i] = 0;
}

// ---------------- x0 fp32 -> bf16 (padded to K0pad) ----------------
__global__ __launch_bounds__(256) void convA_kernel(const float* __restrict__ A,
    unsigned short* __restrict__ Ab, int M, int K, int Kpad) {
  int i = blockIdx.x * blockDim.x + threadIdx.x;           // one per 8 outputs
  int row = i >> 6;                                        // Kpad/8 = 64 chunks
  int koff = (i & 63) * 8;
  if (row >= M) return;
  const float* ap = A + (size_t)row * K;
  unsigned short v[8];
  if (koff + 8 <= K) {
    float4 q0 = ((const float4*)(ap + koff))[0];
    float4 q1 = ((const float4*)(ap + koff))[1];
    v[0] = bf16r(q0.x); v[1] = bf16r(q0.y); v[2] = bf16r(q0.z); v[3] = bf16r(q0.w);
    v[4] = bf16r(q1.x); v[5] = bf16r(q1.y); v[6] = bf16r(q1.z); v[7] = bf16r(q1.w);
  } else {
#pragma unroll
    for (int k = 0; k < 8; ++k)
      v[k] = (koff + k < K) ? bf16r(ap[koff + k]) : (unsigned short)0;
  }
  *(uint4*)(Ab + (size_t)row * Kpad + koff) = *(const uint4*)v;
}

// ---------------- CSR build: segmented count + position (fallback path) -----
__global__ __launch_bounds__(256) void count3_kernel(P3c adj,
    int* __restrict__ segcnt, int* __restrict__ posb, int E, int N) {
  int i = blockIdx.x * blockDim.x + threadIdx.x;
  int o = blockIdx.y;
  if (i < E) {
    int d = adj.p[o][E + i];
    int s = i >> SEGSH;
    if (s > SSEG - 1) s = SSEG - 1;
    posb[(size_t)o * E + i] = atomicAdd(&segcnt[((size_t)o * SSEG + s) * N + d], 1);
  }
}

// per-node prefix over the 8 segment counts: segcnt -> segbase (in place),
// totals -> cntb (feeds the unchanged scan pipeline). Coalesced per s-step.
__global__ __launch_bounds__(256) void nodeseg_scan_kernel(int* __restrict__ segcnt,
    int* __restrict__ cntb, int N) {
  int n = blockIdx.x * blockDim.x + threadIdx.x;
  int o = blockIdx.y;
  if (n >= N) return;
  int run = 0;
#pragma unroll
  for (int s = 0; s < SSEG; ++s) {
    size_t idx = ((size_t)o * SSEG + s) * N + n;
    int c = segcnt[idx];
    segcnt[idx] = run;
    run += c;
  }
  cntb[o * N + n] = run;
}

#define SCAN_T 256
#define SCAN_VPT 8
#define SCAN_TILE 2048

__global__ __launch_bounds__(SCAN_T) void scan1_kernel(const int* __restrict__ cntb,
    int* __restrict__ rowptrb, int* __restrict__ bsums, int N) {
  __shared__ int lds[SCAN_T];
  const int o = blockIdx.y;
  const int* cnt = cntb + o * N;
  int* rowptr = rowptrb + o * (N + 1);
  int t = threadIdx.x;
  int base = blockIdx.x * SCAN_TILE + t * SCAN_VPT;
  int v[SCAN_VPT];
  int s = 0;
#pragma unroll
  for (int i = 0; i < SCAN_VPT; ++i) {
    int idx = base + i;
    int x = (idx < N) ? cnt[idx] : 0;
    s += x;
    v[i] = s;
  }
  lds[t] = s;
  __syncthreads();
  for (int off = 1; off < SCAN_T; off <<= 1) {
    int add = (t >= off) ? lds[t - off] : 0;
    __syncthreads();
    lds[t] += add;
    __syncthreads();
  }
  int excl = (t > 0) ? lds[t - 1] : 0;
#pragma unroll
  for (int i = 0; i < SCAN_VPT; ++i) {
    int idx = base + i;
    if (idx < N) rowptr[idx + 1] = excl + v[i];
  }
  if (t == SCAN_T - 1) bsums[o * 64 + blockIdx.x] = lds[t];
}

__global__ void scan2_kernel(int* bsums, int nb, int* rowptrb, int N) {
  if (threadIdx.x == 0 && blockIdx.x == 0) {
    for (int o = 0; o < 3; ++o) {
      int run = 0;
      for (int i = 0; i < nb; ++i) {
        int x = bsums[o * 64 + i];
        bsums[o * 64 + i] = run;
        run += x;
      }
      rowptrb[o * (N + 1)] = 0;
    }
  }
}

__global__ __launch_bounds__(256) void scan3_kernel(int* __restrict__ rowptrb,
    const int* __restrict__ bsums, int N) {
  int idx = blockIdx.x * blockDim.x + threadIdx.x;
  int o = blockIdx.y;
  if (idx < N) rowptrb[o * (N + 1) + idx + 1] += bsums[o * 64 + idx / SCAN_TILE];
}

// atomic-free fill: pos = segbase[s][d] + within-segment pos (posb).
__global__ __launch_bounds__(256) void fill3_kernel(P3c adj,
    const int* __restrict__ rowptrb, const int* __restrict__ segcnt,
    const int* __restrict__ posb, int* __restrict__ colvb, int E, int N) {
  int i = blockIdx.x * blockDim.x + threadIdx.x;
  int o = blockIdx.y;
  if (i < E) {
    const int* a = adj.p[o];
    int d = a[E + i];
    int s = i >> SEGSH;
    if (s > SSEG - 1) s = SSEG - 1;
    int pos = segcnt[((size_t)o * SSEG + s) * N + d] + posb[(size_t)o * E + i];
    colvb[(size_t)o * E + rowptrb[o * (N + 1) + d] + pos] = a[i];
  }
}

// ---------------- per-edge attention weights (node-parallel, CSR order) ------
__global__ __launch_bounds__(256) void alpha3_kernel(const int* __restrict__ rowptrB,
    const int* __restrict__ colvB, const float2* __restrict__ alsB,
    const float2* __restrict__ aldB, float2* __restrict__ alphB, int N, int E) {
  int w = blockIdx.x * blockDim.x + threadIdx.x;
  int o = blockIdx.y;
  if (w >= N) return;
  const int* rowptr = rowptrB + o * (N + 1);
  const int* colv = colvB + (size_t)o * E;
  const float2* als = alsB + (size_t)o * N;
  const float2 b = (aldB + (size_t)o * N)[w];
  float2* alph = alphB + (size_t)o * E;
  const int beg = rowptr[w], end = rowptr[w + 1];
  for (int j = beg; j < end; ++j) {
    int s = colv[j];
    float2 a = als[s];
    alph[j] = make_float2(__expf(leakyf(a.x + b.x)), __expf(leakyf(a.y + b.y)));
  }
}

// ---------------- weight transpose+convert (batched) ----------------
__global__ __launch_bounds__(256) void conv_bt3_kernel(P3f W,
    unsigned short* __restrict__ BtB, int K, int NC, int Kpad) {
  int n = blockIdx.y;
  int o = blockIdx.z;
  int k = blockIdx.x * 256 + threadIdx.x;
  if (k >= Kpad) return;
  float v = (k < K) ? W.p[o][(size_t)k * NC + n] : 0.f;
  BtB[(size_t)o * NC * Kpad + (size_t)n * Kpad + k] = bf16r(v);
}

// ---------------- MFMA bf16 GEMM body (shared by plain + fused kernels) -----
#define GBM 128
#define LDSTRIDE 40

template<int NT>
__device__ __forceinline__ void gemm_body(int m0, int o, int t,
    const unsigned short* __restrict__ Ab, const unsigned short* __restrict__ BtB,
    P3f asp, P3f adp, unsigned short* __restrict__ CbB,
    float2* __restrict__ alsB, float2* __restrict__ aldB, int M, int Kpad,
    unsigned short* As, unsigned short* Bs) {
  constexpr int NC = NT * 16;
  constexpr int CH = NT * 8;          // per-head channels
  const int wave = t >> 6, lane = t & 63;
  const int quad = lane >> 4, l16 = lane & 15;
  const unsigned short* Bt = BtB + (size_t)o * NC * Kpad;
  unsigned short* Cb = CbB + (size_t)o * M * NC;
  float2* al_s = alsB + (size_t)o * M;
  float2* al_d = aldB + (size_t)o * M;
  const float* a_src = asp.p[o];
  const float* a_dst = adp.p[o];

  f32x4 acc[2][NT];
#pragma unroll
  for (int i = 0; i < 2; ++i)
#pragma unroll
    for (int j = 0; j < NT; ++j) acc[i][j] = (f32x4){0.f, 0.f, 0.f, 0.f};

  const int arow = t >> 1;
  const int akoff = (t & 1) * 16;
  const int gm = m0 + arow;
  const unsigned short* arowp = Ab + (size_t)gm * Kpad;
  const unsigned short* browp = Bt + (size_t)arow * Kpad;

  for (int k0 = 0; k0 < Kpad; k0 += 32) {
    if (k0) __syncthreads();
    const int kb = k0 + akoff;
    {
      uint4 q0 = {0, 0, 0, 0}, q1 = {0, 0, 0, 0};
      if (gm < M) {
        const uint4* p = (const uint4*)(arowp + kb);
        q0 = p[0]; q1 = p[1];
      }
      short8* dst = (short8*)&As[arow * LDSTRIDE + akoff];
      union { uint4 q; short8 s; } c0, c1;
      c0.q = q0; c1.q = q1;
      dst[0] = c0.s;
      dst[1] = c1.s;
    }
    if (arow < NC) {
      const uint4* p = (const uint4*)(browp + kb);
      uint4 q0 = p[0], q1 = p[1];
      short8* dst = (short8*)&Bs[arow * LDSTRIDE + akoff];
      union { uint4 q; short8 s; } c0, c1;
      c0.q = q0; c1.q = q1;
      dst[0] = c0.s;
      dst[1] = c1.s;
    }
    __syncthreads();
    short8 af[2];
#pragma unroll
    for (int rt = 0; rt < 2; ++rt)
      af[rt] = *(const short8*)&As[(wave * 32 + rt * 16 + l16) * LDSTRIDE + quad * 8];
    short8 bfv[NT];
#pragma unroll
    for (int ct = 0; ct < NT; ++ct)
      bfv[ct] = *(const short8*)&Bs[(ct * 16 + l16) * LDSTRIDE + quad * 8];
#pragma unroll
    for (int rt = 0; rt < 2; ++rt)
#pragma unroll
      for (int ct = 0; ct < NT; ++ct)
        acc[rt][ct] = __builtin_amdgcn_mfma_f32_16x16x32_bf16(af[rt], bfv[ct],
                                                              acc[rt][ct], 0, 0, 0);
  }
  // ---- epilogue: bf16 h store + fused al_s/al_d ----
  float asv[NT], adv[NT];
#pragma unroll
  for (int ct = 0; ct < NT; ++ct) {
    int col = ct * 16 + l16;
    asv[ct] = a_src[col];
    adv[ct] = a_dst[col];
  }
#pragma unroll
  for (int rt = 0; rt < 2; ++rt) {
    int gr0 = m0 + wave * 32 + rt * 16 + quad * 4;
#pragma unroll
    for (int r = 0; r < 4; ++r) {
      int gr = gr0 + r;
      float ps0 = 0.f, ps1 = 0.f, pd0 = 0.f, pd1 = 0.f;
#pragma unroll
      for (int ct = 0; ct < NT; ++ct) {
        int col = ct * 16 + l16;
        float v = acc[rt][ct][r];
        if (gr < M) Cb[(size_t)gr * NC + col] = bf16r(v);
        if (col < CH) { ps0 += v * asv[ct]; pd0 += v * adv[ct]; }
        else          { ps1 += v * asv[ct]; pd1 += v * adv[ct]; }
      }
#pragma unroll
      for (int off = 1; off < 16; off <<= 1) {
        ps0 += __shfl_xor(ps0, off, 64);
        ps1 += __shfl_xor(ps1, off, 64);
        pd0 += __shfl_xor(pd0, off, 64);
        pd1 += __shfl_xor(pd1, off, 64);
      }
      if (l16 == 0 && gr < M) {
        al_s[gr] = make_float2(ps0, ps1);
        al_d[gr] = make_float2(pd0, pd1);
      }
    }
  }
}

template<int NT>
__global__ __launch_bounds__(256) void mfma_gemm_kernel(
    const unsigned short* __restrict__ Ab, const unsigned short* __restrict__ BtB,
    P3f asp, P3f adp, unsigned short* __restrict__ CbB,
    float2* __restrict__ alsB, float2* __restrict__ aldB, int M, int Kpad) {
  __shared__ unsigned short As[GBM * LDSTRIDE];
  __shared__ unsigned short Bs[NT * 16 * LDSTRIDE];
  gemm_body<NT>(blockIdx.x * GBM, blockIdx.y, threadIdx.x,
                Ab, BtB, asp, adp, CbB, alsB, aldB, M, Kpad, As, Bs);
}

// ---------------- fused GEMM L0 + segmented count ----------------------------
// Interleaved dispatch: every 9th x-block (x%9==0, x/9<nbG) runs a GEMM L0
// block; the rest run count blocks (segmented counters). Coverage proof:
// x in [0,9*nbG). rem==0 -> gx=0..nbG-1 each once. rem!=0 ->
// nG=(x+8)/9=gx+1<=nbG, c=x-nG=8*gx+rem-1 contiguous over [0,8*nbG);
// c>=nbE tail guarded by i<E.
__global__ __launch_bounds__(256) void gemm0_count_kernel(
    const unsigned short* __restrict__ Ab, const unsigned short* __restrict__ BtB,
    P3f asp, P3f adp, unsigned short* __restrict__ CbB,
    float2* __restrict__ alsB, float2* __restrict__ aldB, int M, int Kpad,
    P3c adj, int* __restrict__ segcnt, int* __restrict__ posb, int E, int N,
    int nbG) {
  __shared__ unsigned short As[GBM * LDSTRIDE];
  __shared__ unsigned short Bs[128 * LDSTRIDE];
  const int x = blockIdx.x;
  const int o = blockIdx.y;
  const int gx = x / 9;
  const int rem = x - gx * 9;
  if (rem == 0 && gx < nbG) {
    gemm_body<8>(gx * GBM, o, threadIdx.x,
                 Ab, BtB, asp, adp, CbB, alsB, aldB, M, Kpad, As, Bs);
  } else {
    int nG = (x + 8) / 9;
    if (nG > nbG) nG = nbG;
    const int c = x - nG;                 // count-block index
    const int i = c * 256 + threadIdx.x;
    if (i < E) {
      int d = adj.p[o][E + i];
      int s = i >> SEGSH;
      if (s > SSEG - 1) s = SSEG - 1;
      posb[(size_t)o * E + i] = atomicAdd(&segcnt[((size_t)o * SSEG + s) * N + d], 1);
    }
  }
}

// ---------------- GAT aggregate: 4 dst nodes per wave, precomputed alpha ----
// R14 version (proven best): natural node order, 4 edges/iter, slot-uniform
// exec-masked guards on gathers and fma chains.
template<int C, int CONCAT>
__global__ __launch_bounds__(256) void gat_slot4_kernel(
    const unsigned short* __restrict__ hB, const float2* __restrict__ alsB,
    const float2* __restrict__ aldB, const int* __restrict__ rowptrB,
    const int* __restrict__ colvB, const float2* __restrict__ alphB,
    P3f biasp, unsigned short* __restrict__ outB, int N, int E) {
  constexpr int HC = 2 * C;
  constexpr int FLd = HC / 8;       // active h lanes per slot: 16 (C=64) / 10 (C=40)
  constexpr int HB = C / 8;         // head boundary in lane units: 8 / 5
  constexpr int OW = CONCAT ? HC : C;
  const int o = blockIdx.y;
  const unsigned short* h = hB + (size_t)o * N * HC;
  const float2* al_s = alsB + (size_t)o * N;
  const float2* al_d = aldB + (size_t)o * N;
  const int* rowptr = rowptrB + o * (N + 1);
  const int* colv = colvB + (size_t)o * E;
  const float2* alph = alphB + (size_t)o * E;
  const float* bias = biasp.p[o];
  unsigned short* out = outB + (size_t)o * N * OW;

  const int gw = (blockIdx.x * blockDim.x + threadIdx.x) >> 6;
  const int lane = threadIdx.x & 63;
  const int slot = lane >> 4;
  const int f4 = lane & 15;
  const int w = gw * 4 + slot;
  if (gw * 4 >= N) return;
  const bool vn = w < N;
  const int wc = vn ? w : N - 1;
  const bool hl = f4 < FLd;

  const int beg = rowptr[wc];
  const int deg = vn ? (rowptr[wc + 1] - beg) : 0;
  int md = deg;
  md = max(md, __shfl_xor(md, 32, 64));
  md = max(md, __shfl_xor(md, 16, 64));   // wave-uniform max degree over 4 slots

  const float2 ad = al_d[wc];
  const float2 asf = al_s[wc];
  const float xs0 = __expf(leakyf(asf.x + ad.x));
  const float xs1 = __expf(leakyf(asf.y + ad.y));
  float dp0 = xs0, dp1 = xs1;

  f32x2 acc[4] = {}, acc2[4] = {};
  // self-loop message first (independent of edge loop)
  if (hl) {
    uint4 q = ((const uint4*)(h + (size_t)wc * HC))[f4];
    bf8_fma2(q, (f4 < HB) ? xs0 : xs1, acc);
  }

  const float2 z2 = make_float2(0.f, 0.f);
  for (int t = 0; t < md; t += 4) {
    const int j0 = beg + t;
    const bool v0 = t < deg;
    const bool v1 = t + 1 < deg;
    const bool v2 = t + 2 < deg;
    const bool v3 = t + 3 < deg;
    // guarded index/alpha loads: never OOB (invalid -> 0)
    const int s0 = v0 ? colv[j0] : 0;
    const int s1 = v1 ? colv[j0 + 1] : 0;
    const int s2 = v2 ? colv[j0 + 2] : 0;
    const int s3 = v3 ? colv[j0 + 3] : 0;
    const float2 a0 = v0 ? alph[j0] : z2;
    const float2 a1 = v1 ? alph[j0 + 1] : z2;
    const float2 a2 = v2 ? alph[j0 + 2] : z2;
    const float2 a3 = v3 ? alph[j0 + 3] : z2;
    // h gathers: exec-masked per slot (v[k] is slot-uniform)
    uint4 q0 = make_uint4(0, 0, 0, 0), q1 = q0, q2 = q0, q3 = q0;
    if (v0 && hl) q0 = ((const uint4*)(h + (size_t)s0 * HC))[f4];
    if (v1 && hl) q1 = ((const uint4*)(h + (size_t)s1 * HC))[f4];
    if (v2 && hl) q2 = ((const uint4*)(h + (size_t)s2 * HC))[f4];
    if (v3 && hl) q3 = ((const uint4*)(h + (size_t)s3 * HC))[f4];
    dp0 += (a0.x + a1.x) + (a2.x + a3.x);
    dp1 += (a0.y + a1.y) + (a2.y + a3.y);
    if (v0 && hl) bf8_fma2(q0, (f4 < HB) ? a0.x : a0.y, acc);
    if (v1 && hl) bf8_fma2(q1, (f4 < HB) ? a1.x : a1.y, acc2);
    if (v2 && hl) bf8_fma2(q2, (f4 < HB) ? a2.x : a2.y, acc);
    if (v3 && hl) bf8_fma2(q3, (f4 < HB) ? a3.x : a3.y, acc2);
  }
#pragma unroll
  for (int i = 0; i < 4; ++i) acc[i] += acc2[i];

  const float inv0 = 1.f / (dp0 + 1e-16f), inv1 = 1.f / (dp1 + 1e-16f);
  if (CONCAT) {
    if (vn && hl) {
      const float xx = (f4 < HB) ? inv0 : inv1;
      const float* bp = bias + f4 * 8;
      unsigned int pk[4];
#pragma unroll
      for (int i = 0; i < 4; ++i) {
        unsigned short lo = bf16r(eluf(acc[i][0] * xx + bp[2 * i]));
        unsigned short hi = bf16r(eluf(acc[i][1] * xx + bp[2 * i + 1]));
        pk[i] = (unsigned int)lo | ((unsigned int)hi << 16);
      }
      ((uint4*)(out + (size_t)w * OW + f4 * 8))[0] = make_uint4(pk[0], pk[1], pk[2], pk[3]);
    }
  } else {
    // mean over 2 heads: head-1 partials live at f4 in [HB, 2*HB) of same slot
    float p[8];
#pragma unroll
    for (int i = 0; i < 4; ++i) {
      p[2 * i]     = __shfl(acc[i][0], lane + HB, 64);
      p[2 * i + 1] = __shfl(acc[i][1], lane + HB, 64);
    }
    if (vn && f4 < HB) {
      const float* bp = bias + f4 * 8;
      unsigned int pk[4];
#pragma unroll
      for (int i = 0; i < 4; ++i) {
        float v0 = 0.5f * (acc[i][0] * inv0 + p[2 * i] * inv1) + bp[2 * i];
        float v1 = 0.5f * (acc[i][1] * inv0 + p[2 * i + 1] * inv1) + bp[2 * i + 1];
        pk[i] = (unsigned int)bf16r(eluf(v0)) | ((unsigned int)bf16r(eluf(v1)) << 16);
      }
      ((uint4*)(out + (size_t)w * OW + f4 * 8))[0] = make_uint4(pk[0], pk[1], pk[2], pk[3]);
    }
  }
}

// ---------------- order-mix (bf16 states in; bf16 or fp32 out) ----------------
template<int BF16OUT>
__global__ __launch_bounds__(256) void mixb_kernel(const unsigned short* __restrict__ sb,
    const float* __restrict__ Wm, const float* __restrict__ wf,
    void* __restrict__ out, int perU) {
  int i = blockIdx.x * blockDim.x + threadIdx.x;
  if (i >= perU) return;
  const unsigned int* sp = (const unsigned int*)sb;
  unsigned int u0 = sp[i];
  unsigned int u1 = sp[perU + i];
  unsigned int u2 = sp[2 * perU + i];
  float a0 = bflo(u0), a1 = bfhi(u0);
  float b0 = bflo(u1), b1 = bfhi(u1);
  float c0 = bflo(u2), c1 = bfhi(u2);
  float r0 = 0.f, r1 = 0.f;
#pragma unroll
  for (int j = 0; j < 3; ++j) {
    float w0 = Wm[j], w1 = Wm[3 + j], w2 = Wm[6 + j], wj = wf[j];
    r0 += wj * eluf(a0 * w0 + b0 * w1 + c0 * w2);
    r1 += wj * eluf(a1 * w0 + b1 * w1 + c1 * w2);
  }
  if (BF16OUT) {
    ((unsigned int*)out)[i] = (unsigned int)bf16r(r0) | ((unsigned int)bf16r(r1) << 16);
  } else {
    ((float2*)out)[i] = make_float2(r0, r1);
  }
}

// ---------------- log_softmax ----------------
__global__ __launch_bounds__(256) void log_softmax_kernel(const float* __restrict__ x,
    float* __restrict__ out, int N, int C) {
  int w = (blockIdx.x * blockDim.x + threadIdx.x) >> 6;
  int lane = threadIdx.x & 63;
  if (w >= N) return;
  float v = (lane < C) ? x[(size_t)w * C + lane] : -INFINITY;
  float mx = v;
#pragma unroll
  for (int off = 1; off < 64; off <<= 1) mx = fmaxf(mx, __shfl_xor(mx, off, 64));
  float ex = (lane < C) ? expf(v - mx) : 0.f;
  float s = ex;
#pragma unroll
  for (int off = 1; off < 64; off <<= 1) s += __shfl_xor(s, off, 64);
  if (lane < C) out[(size_t)w * C + lane] = v - mx - logf(s);
}

// ---------------------------------------------------------------------------
extern "C" void kernel_launch(void* const* d_in, const int* in_sizes, int n_in,
                              void* d_out, int out_size, void* d_ws, size_t ws_size,
                              hipStream_t stream) {
  const int F_IN = 500;
  const int N = in_sizes[0] / F_IN;     // 50000
  const int E = in_sizes[1] / 2;        // 800000
  const int HC0 = 128;
  const int HC1 = 80;
  const int C1 = 40;
  const int K0pad = 512, K1pad = 128;

  const float* x0 = (const float*)d_in[0];
  P3c adj;
  adj.p[0] = (const int*)d_in[1];
  adj.p[1] = (const int*)d_in[2];
  adj.p[2] = (const int*)d_in[3];
  P3f W0p, as0p, ad0p, b0p, W1p, as1p, ad1p, b1p;
  for (int o = 0; o < 3; ++o) {
    W0p.p[o]  = (const float*)d_in[4 + 4 * o + 0];
    as0p.p[o] = (const float*)d_in[4 + 4 * o + 1];
    ad0p.p[o] = (const float*)d_in[4 + 4 * o + 2];
    b0p.p[o]  = (const float*)d_in[4 + 4 * o + 3];
    W1p.p[o]  = (const float*)d_in[16 + 4 * o + 0];
    as1p.p[o] = (const float*)d_in[16 + 4 * o + 1];
    ad1p.p[o] = (const float*)d_in[16 + 4 * o + 2];
    b1p.p[o]  = (const float*)d_in[16 + 4 * o + 3];
  }
  const float* agg0W = (const float*)d_in[28];
  const float* agg0w = (const float*)d_in[29];
  const float* agg1W = (const float*)d_in[30];
  const float* agg1w = (const float*)d_in[31];

  // ---- workspace layout ----
  char* ws = (char*)d_ws;
  size_t off = 0;
  auto alloc = [&](size_t bytes) -> void* {
    off = (off + 255) & ~(size_t)255;
    void* p = ws + off;
    off += bytes;
    return p;
  };
  int* rowptrb = (int*)alloc((size_t)3 * (N + 1) * 4);
  int* colvb   = (int*)alloc((size_t)3 * E * 4);
  int* cntb    = (int*)alloc((size_t)3 * N * 4);
  int* bsums   = (int*)alloc(3 * 64 * 4);
  unsigned short* x0b = (unsigned short*)alloc((size_t)N * K0pad * 2);    // bf16 x0
  unsigned short* hB  = (unsigned short*)alloc((size_t)3 * N * HC0 * 2);  // bf16 h
  unsigned short* stB = (unsigned short*)alloc((size_t)3 * N * HC0 * 2);  // bf16 states; block0 reused as bf16 x1
  float* x2 = (float*)alloc((size_t)N * C1 * 4);
  float2* alsB = (float2*)alloc((size_t)3 * N * 8);
  float2* aldB = (float2*)alloc((size_t)3 * N * 8);
  unsigned short* Bt0B = (unsigned short*)alloc((size_t)3 * HC0 * K0pad * 2);
  unsigned short* Bt1B = (unsigned short*)alloc((size_t)3 * HC1 * K1pad * 2);
  // Aliases (all rewritten before first read on every run, in stream order):
  //  - alphb (19.2MB) aliases x0b (51.2MB): x0b dead after fused GEMM L0;
  //    alpha3 runs after it.
  //  - posb (9.6MB) + segcnt (4.8MB) alias stB (38.4MB): fused kernel writes
  //    posb/segcnt (count path) + hB (GEMM path) -> they must NOT alias hB.
  //    Both dead after fill3; stB first written by gat L0 (after fill3).
  float2* alphb = (float2*)x0b;
  int* posb   = (int*)stB;
  int* segcnt = (int*)(stB + (size_t)3 * E * 2);   // 3*E ints = 3*E*2 shorts
  (void)ws_size;

  const int TB = 256;
  const int nbE = (E + TB - 1) / TB;
  const int nbN = (N + TB - 1) / TB;
  const int scanBlocks = (N + SCAN_TILE - 1) / SCAN_TILE;
  const int gemmBlocks = (N + GBM - 1) / GBM;
  const int slot4Blocks = (int)(((size_t)((N + 3) / 4) * 64 + TB - 1) / TB);
  const int lsBlocks = (int)(((size_t)N * 64 + TB - 1) / TB);

  // ---- conversions ----
  convA_kernel<<<(int)(((size_t)N * 64 + TB - 1) / TB), TB, 0, stream>>>(
      x0, x0b, N, F_IN, K0pad);
  conv_bt3_kernel<<<dim3((K0pad + 255) / 256, HC0, 3), TB, 0, stream>>>(W0p, Bt0B, F_IN, HC0, K0pad);
  conv_bt3_kernel<<<dim3((K1pad + 255) / 256, HC1, 3), TB, 0, stream>>>(W1p, Bt1B, HC0, HC1, K1pad);

  // ---- fused GEMM L0 + segmented edge count (independent, co-scheduled) ----
  zero_int_kernel<<<(3 * SSEG * N + TB - 1) / TB, TB, 0, stream>>>(segcnt, 3 * SSEG * N);
  if (8 * gemmBlocks >= nbE) {
    gemm0_count_kernel<<<dim3(gemmBlocks * 9, 3), TB, 0, stream>>>(
        x0b, Bt0B, as0p, ad0p, hB, alsB, aldB, N, K0pad,
        adj, segcnt, posb, E, N, gemmBlocks);
  } else {  // size fallback: sequential (correctness-preserving)
    count3_kernel<<<dim3(nbE, 3), TB, 0, stream>>>(adj, segcnt, posb, E, N);
    mfma_gemm_kernel<8><<<dim3(gemmBlocks, 3), TB, 0, stream>>>(
        x0b, Bt0B, as0p, ad0p, hB, alsB, aldB, N, K0pad);
  }

  // ---- CSR finalize ----
  nodeseg_scan_kernel<<<dim3(nbN, 3), TB, 0, stream>>>(segcnt, cntb, N);
  scan1_kernel<<<dim3(scanBlocks, 3), SCAN_T, 0, stream>>>(cntb, rowptrb, bsums, N);
  scan2_kernel<<<1, 64, 0, stream>>>(bsums, scanBlocks, rowptrb, N);
  scan3_kernel<<<dim3(nbN, 3), TB, 0, stream>>>(rowptrb, bsums, N);
  fill3_kernel<<<dim3(nbE, 3), TB, 0, stream>>>(adj, rowptrb, segcnt, posb, colvb, E, N);

  // ---- layer 0 (concat) ----
  alpha3_kernel<<<dim3(nbN, 3), TB, 0, stream>>>(rowptrb, colvb, alsB, aldB, alphb, N, E);
  gat_slot4_kernel<64, 1><<<dim3(slot4Blocks, 3), TB, 0, stream>>>(
      hB, alsB, aldB, rowptrb, colvb, alphb, b0p, stB, N, E);
  mixb_kernel<1><<<((N * HC0 / 2) + TB - 1) / TB, TB, 0, stream>>>(
      stB, agg0W, agg0w, stB, N * HC0 / 2);   // in-place bf16 x1 over state block 0

  // ---- layer 1 (mean over heads) ----
  mfma_gemm_kernel<5><<<dim3(gemmBlocks, 3), TB, 0, stream>>>(
      stB, Bt1B, as1p, ad1p, hB, alsB, aldB, N, K1pad);
  alpha3_kernel<<<dim3(nbN, 3), TB, 0, stream>>>(rowptrb, colvb, alsB, aldB, alphb, N, E);
  gat_slot4_kernel<40, 0><<<dim3(slot4Blocks, 3), TB, 0, stream>>>(
      hB, alsB, aldB, rowptrb, colvb, alphb, b1p, stB, N, E);
  mixb_kernel<0><<<((N * C1 / 2) + TB - 1) / TB, TB, 0, stream>>>(
      stB, agg1W, agg1w, x2, N * C1 / 2);

  log_softmax_kernel<<<lsBlocks, TB, 0, stream>>>(x2, (float*)d_out, N, C1);
}

// Round 13
// 757.866 us; speedup vs baseline: 1.0266x; 1.0266x over previous
//
#include <hip/hip_runtime.h>
#include <cstdint>
#include <cstddef>
#include <math.h>

// ---------------------------------------------------------------------------
// SturtGAT round 21: revert R20's segmentation (null result: fused dispatch
// 130->129us, overhead cost 18us -- atomic path is THROUGHPUT-limited, not
// contention-limited; falsified twice) back to R19's measured-best structure
// (760us). New: mixb<0> + log_softmax fused into mixfin (one wave = 2 nodes,
// mix in-register, half-wave shuffle reductions, direct d_out write) --
// removes the 8MB x2 roundtrip + one launch. Arithmetic identical.
// ---------------------------------------------------------------------------

typedef __attribute__((ext_vector_type(8))) short short8;   // 8 bf16 (4 VGPRs)
typedef __attribute__((ext_vector_type(4))) float f32x4;    // 4 fp32 acc
typedef __attribute__((ext_vector_type(2))) float f32x2;    // packed fma pair

struct P3f { const float* p[3]; };
struct P3c { const int* p[3]; };

__device__ __forceinline__ float leakyf(float x) { return x > 0.f ? x : 0.2f * x; }
__device__ __forceinline__ float eluf(float x)   { return x > 0.f ? x : expm1f(x); }

__device__ __forceinline__ unsigned short bf16r(float x) {  // RNE fp32->bf16
  unsigned int u = __float_as_uint(x);
  u += 0x7fffu + ((u >> 16) & 1u);
  return (unsigned short)(u >> 16);
}
__device__ __forceinline__ float bflo(unsigned int u) { return __uint_as_float(u << 16); }
__device__ __forceinline__ float bfhi(unsigned int u) { return __uint_as_float(u & 0xffff0000u); }

// unpack 8 bf16 (uint4), packed-fma into a[0..3] (f32x2 each) with scalar xx
__device__ __forceinline__ void bf8_fma2(uint4 q, float xx, f32x2* a) {
  f32x2 v0 = {bflo(q.x), bfhi(q.x)};
  f32x2 v1 = {bflo(q.y), bfhi(q.y)};
  f32x2 v2 = {bflo(q.z), bfhi(q.z)};
  f32x2 v3 = {bflo(q.w), bfhi(q.w)};
  a[0] += xx * v0;
  a[1] += xx * v1;
  a[2] += xx * v2;
  a[3] += xx * v3;
}

// ---------------- utility ----------------
__global__ __launch_bounds__(256) void zero_int_kernel(int* p, int n) {
  int i = blockIdx.x * blockDim.x + threadIdx.x;
  if (i < n) p[i] = 0;
}

// ---------------- x0 fp32 -> bf16 (padded to K0pad) ----------------
__global__ __launch_bounds__(256) void convA_kernel(const float* __restrict__ A,
    unsigned short* __restrict__ Ab, int M, int K, int Kpad) {
  int i = blockIdx.x * blockDim.x + threadIdx.x;           // one per 8 outputs
  int row = i >> 6;                                        // Kpad/8 = 64 chunks
  int koff = (i & 63) * 8;
  if (row >= M) return;
  const float* ap = A + (size_t)row * K;
  unsigned short v[8];
  if (koff + 8 <= K) {
    float4 q0 = ((const float4*)(ap + koff))[0];
    float4 q1 = ((const float4*)(ap + koff))[1];
    v[0] = bf16r(q0.x); v[1] = bf16r(q0.y); v[2] = bf16r(q0.z); v[3] = bf16r(q0.w);
    v[4] = bf16r(q1.x); v[5] = bf16r(q1.y); v[6] = bf16r(q1.z); v[7] = bf16r(q1.w);
  } else {
#pragma unroll
    for (int k = 0; k < 8; ++k)
      v[k] = (koff + k < K) ? bf16r(ap[koff + k]) : (unsigned short)0;
  }
  *(uint4*)(Ab + (size_t)row * Kpad + koff) = *(const uint4*)v;
}

// ---------------- CSR build: count + position (fallback path) ---------------
__global__ __launch_bounds__(256) void count3_kernel(P3c adj, int* __restrict__ cntb,
    int* __restrict__ posb, int E, int N) {
  int i = blockIdx.x * blockDim.x + threadIdx.x;
  int o = blockIdx.y;
  if (i < E) {
    int d = adj.p[o][E + i];
    posb[(size_t)o * E + i] = atomicAdd(&cntb[o * N + d], 1);
  }
}

#define SCAN_T 256
#define SCAN_VPT 8
#define SCAN_TILE 2048

__global__ __launch_bounds__(SCAN_T) void scan1_kernel(const int* __restrict__ cntb,
    int* __restrict__ rowptrb, int* __restrict__ bsums, int N) {
  __shared__ int lds[SCAN_T];
  const int o = blockIdx.y;
  const int* cnt = cntb + o * N;
  int* rowptr = rowptrb + o * (N + 1);
  int t = threadIdx.x;
  int base = blockIdx.x * SCAN_TILE + t * SCAN_VPT;
  int v[SCAN_VPT];
  int s = 0;
#pragma unroll
  for (int i = 0; i < SCAN_VPT; ++i) {
    int idx = base + i;
    int x = (idx < N) ? cnt[idx] : 0;
    s += x;
    v[i] = s;
  }
  lds[t] = s;
  __syncthreads();
  for (int off = 1; off < SCAN_T; off <<= 1) {
    int add = (t >= off) ? lds[t - off] : 0;
    __syncthreads();
    lds[t] += add;
    __syncthreads();
  }
  int excl = (t > 0) ? lds[t - 1] : 0;
#pragma unroll
  for (int i = 0; i < SCAN_VPT; ++i) {
    int idx = base + i;
    if (idx < N) rowptr[idx + 1] = excl + v[i];
  }
  if (t == SCAN_T - 1) bsums[o * 64 + blockIdx.x] = lds[t];
}

__global__ void scan2_kernel(int* bsums, int nb, int* rowptrb, int N) {
  if (threadIdx.x == 0 && blockIdx.x == 0) {
    for (int o = 0; o < 3; ++o) {
      int run = 0;
      for (int i = 0; i < nb; ++i) {
        int x = bsums[o * 64 + i];
        bsums[o * 64 + i] = run;
        run += x;
      }
      rowptrb[o * (N + 1)] = 0;
    }
  }
}

__global__ __launch_bounds__(256) void scan3_kernel(int* __restrict__ rowptrb,
    const int* __restrict__ bsums, int N) {
  int idx = blockIdx.x * blockDim.x + threadIdx.x;
  int o = blockIdx.y;
  if (idx < N) rowptrb[o * (N + 1) + idx + 1] += bsums[o * 64 + idx / SCAN_TILE];
}

// atomic-free fill: position comes from posb (recorded by count path).
__global__ __launch_bounds__(256) void fill3_kernel(P3c adj,
    const int* __restrict__ rowptrb, const int* __restrict__ posb,
    int* __restrict__ colvb, int E, int N) {
  int i = blockIdx.x * blockDim.x + threadIdx.x;
  int o = blockIdx.y;
  if (i < E) {
    const int* a = adj.p[o];
    int d = a[E + i];
    int pos = posb[(size_t)o * E + i];
    colvb[(size_t)o * E + rowptrb[o * (N + 1) + d] + pos] = a[i];
  }
}

// ---------------- per-edge attention weights (node-parallel, CSR order) ------
__global__ __launch_bounds__(256) void alpha3_kernel(const int* __restrict__ rowptrB,
    const int* __restrict__ colvB, const float2* __restrict__ alsB,
    const float2* __restrict__ aldB, float2* __restrict__ alphB, int N, int E) {
  int w = blockIdx.x * blockDim.x + threadIdx.x;
  int o = blockIdx.y;
  if (w >= N) return;
  const int* rowptr = rowptrB + o * (N + 1);
  const int* colv = colvB + (size_t)o * E;
  const float2* als = alsB + (size_t)o * N;
  const float2 b = (aldB + (size_t)o * N)[w];
  float2* alph = alphB + (size_t)o * E;
  const int beg = rowptr[w], end = rowptr[w + 1];
  for (int j = beg; j < end; ++j) {
    int s = colv[j];
    float2 a = als[s];
    alph[j] = make_float2(__expf(leakyf(a.x + b.x)), __expf(leakyf(a.y + b.y)));
  }
}

// ---------------- weight transpose+convert (batched) ----------------
__global__ __launch_bounds__(256) void conv_bt3_kernel(P3f W,
    unsigned short* __restrict__ BtB, int K, int NC, int Kpad) {
  int n = blockIdx.y;
  int o = blockIdx.z;
  int k = blockIdx.x * 256 + threadIdx.x;
  if (k >= Kpad) return;
  float v = (k < K) ? W.p[o][(size_t)k * NC + n] : 0.f;
  BtB[(size_t)o * NC * Kpad + (size_t)n * Kpad + k] = bf16r(v);
}

// ---------------- MFMA bf16 GEMM body (shared by plain + fused kernels) -----
#define GBM 128
#define LDSTRIDE 40

template<int NT>
__device__ __forceinline__ void gemm_body(int m0, int o, int t,
    const unsigned short* __restrict__ Ab, const unsigned short* __restrict__ BtB,
    P3f asp, P3f adp, unsigned short* __restrict__ CbB,
    float2* __restrict__ alsB, float2* __restrict__ aldB, int M, int Kpad,
    unsigned short* As, unsigned short* Bs) {
  constexpr int NC = NT * 16;
  constexpr int CH = NT * 8;          // per-head channels
  const int wave = t >> 6, lane = t & 63;
  const int quad = lane >> 4, l16 = lane & 15;
  const unsigned short* Bt = BtB + (size_t)o * NC * Kpad;
  unsigned short* Cb = CbB + (size_t)o * M * NC;
  float2* al_s = alsB + (size_t)o * M;
  float2* al_d = aldB + (size_t)o * M;
  const float* a_src = asp.p[o];
  const float* a_dst = adp.p[o];

  f32x4 acc[2][NT];
#pragma unroll
  for (int i = 0; i < 2; ++i)
#pragma unroll
    for (int j = 0; j < NT; ++j) acc[i][j] = (f32x4){0.f, 0.f, 0.f, 0.f};

  const int arow = t >> 1;
  const int akoff = (t & 1) * 16;
  const int gm = m0 + arow;
  const unsigned short* arowp = Ab + (size_t)gm * Kpad;
  const unsigned short* browp = Bt + (size_t)arow * Kpad;

  for (int k0 = 0; k0 < Kpad; k0 += 32) {
    if (k0) __syncthreads();
    const int kb = k0 + akoff;
    {
      uint4 q0 = {0, 0, 0, 0}, q1 = {0, 0, 0, 0};
      if (gm < M) {
        const uint4* p = (const uint4*)(arowp + kb);
        q0 = p[0]; q1 = p[1];
      }
      short8* dst = (short8*)&As[arow * LDSTRIDE + akoff];
      union { uint4 q; short8 s; } c0, c1;
      c0.q = q0; c1.q = q1;
      dst[0] = c0.s;
      dst[1] = c1.s;
    }
    if (arow < NC) {
      const uint4* p = (const uint4*)(browp + kb);
      uint4 q0 = p[0], q1 = p[1];
      short8* dst = (short8*)&Bs[arow * LDSTRIDE + akoff];
      union { uint4 q; short8 s; } c0, c1;
      c0.q = q0; c1.q = q1;
      dst[0] = c0.s;
      dst[1] = c1.s;
    }
    __syncthreads();
    short8 af[2];
#pragma unroll
    for (int rt = 0; rt < 2; ++rt)
      af[rt] = *(const short8*)&As[(wave * 32 + rt * 16 + l16) * LDSTRIDE + quad * 8];
    short8 bfv[NT];
#pragma unroll
    for (int ct = 0; ct < NT; ++ct)
      bfv[ct] = *(const short8*)&Bs[(ct * 16 + l16) * LDSTRIDE + quad * 8];
#pragma unroll
    for (int rt = 0; rt < 2; ++rt)
#pragma unroll
      for (int ct = 0; ct < NT; ++ct)
        acc[rt][ct] = __builtin_amdgcn_mfma_f32_16x16x32_bf16(af[rt], bfv[ct],
                                                              acc[rt][ct], 0, 0, 0);
  }
  // ---- epilogue: bf16 h store + fused al_s/al_d ----
  float asv[NT], adv[NT];
#pragma unroll
  for (int ct = 0; ct < NT; ++ct) {
    int col = ct * 16 + l16;
    asv[ct] = a_src[col];
    adv[ct] = a_dst[col];
  }
#pragma unroll
  for (int rt = 0; rt < 2; ++rt) {
    int gr0 = m0 + wave * 32 + rt * 16 + quad * 4;
#pragma unroll
    for (int r = 0; r < 4; ++r) {
      int gr = gr0 + r;
      float ps0 = 0.f, ps1 = 0.f, pd0 = 0.f, pd1 = 0.f;
#pragma unroll
      for (int ct = 0; ct < NT; ++ct) {
        int col = ct * 16 + l16;
        float v = acc[rt][ct][r];
        if (gr < M) Cb[(size_t)gr * NC + col] = bf16r(v);
        if (col < CH) { ps0 += v * asv[ct]; pd0 += v * adv[ct]; }
        else          { ps1 += v * asv[ct]; pd1 += v * adv[ct]; }
      }
#pragma unroll
      for (int off = 1; off < 16; off <<= 1) {
        ps0 += __shfl_xor(ps0, off, 64);
        ps1 += __shfl_xor(ps1, off, 64);
        pd0 += __shfl_xor(pd0, off, 64);
        pd1 += __shfl_xor(pd1, off, 64);
      }
      if (l16 == 0 && gr < M) {
        al_s[gr] = make_float2(ps0, ps1);
        al_d[gr] = make_float2(pd0, pd1);
      }
    }
  }
}

template<int NT>
__global__ __launch_bounds__(256) void mfma_gemm_kernel(
    const unsigned short* __restrict__ Ab, const unsigned short* __restrict__ BtB,
    P3f asp, P3f adp, unsigned short* __restrict__ CbB,
    float2* __restrict__ alsB, float2* __restrict__ aldB, int M, int Kpad) {
  __shared__ unsigned short As[GBM * LDSTRIDE];
  __shared__ unsigned short Bs[NT * 16 * LDSTRIDE];
  gemm_body<NT>(blockIdx.x * GBM, blockIdx.y, threadIdx.x,
                Ab, BtB, asp, adp, CbB, alsB, aldB, M, Kpad, As, Bs);
}

// ---------------- fused GEMM L0 + count ------------------------------------
// Interleaved dispatch: every 9th x-block (x%9==0, x/9<nbG) runs a GEMM L0
// block; the rest run count blocks. Coverage proof: x in [0,9*nbG). rem==0
// -> gx=0..nbG-1 each once. rem!=0 -> nG=(x+8)/9=gx+1<=nbG, c=x-nG=
// 8*gx+rem-1 contiguous over [0,8*nbG); c>=nbE tail guarded by i<E.
__global__ __launch_bounds__(256) void gemm0_count_kernel(
    const unsigned short* __restrict__ Ab, const unsigned short* __restrict__ BtB,
    P3f asp, P3f adp, unsigned short* __restrict__ CbB,
    float2* __restrict__ alsB, float2* __restrict__ aldB, int M, int Kpad,
    P3c adj, int* __restrict__ cntb, int* __restrict__ posb, int E, int N,
    int nbG) {
  __shared__ unsigned short As[GBM * LDSTRIDE];
  __shared__ unsigned short Bs[128 * LDSTRIDE];
  const int x = blockIdx.x;
  const int o = blockIdx.y;
  const int gx = x / 9;
  const int rem = x - gx * 9;
  if (rem == 0 && gx < nbG) {
    gemm_body<8>(gx * GBM, o, threadIdx.x,
                 Ab, BtB, asp, adp, CbB, alsB, aldB, M, Kpad, As, Bs);
  } else {
    int nG = (x + 8) / 9;
    if (nG > nbG) nG = nbG;
    const int c = x - nG;                 // count-block index
    const int i = c * 256 + threadIdx.x;
    if (i < E) {
      int d = adj.p[o][E + i];
      posb[(size_t)o * E + i] = atomicAdd(&cntb[o * N + d], 1);
    }
  }
}

// ---------------- GAT aggregate: 4 dst nodes per wave, precomputed alpha ----
// R14 version (proven best): natural node order, 4 edges/iter, slot-uniform
// exec-masked guards on gathers and fma chains.
template<int C, int CONCAT>
__global__ __launch_bounds__(256) void gat_slot4_kernel(
    const unsigned short* __restrict__ hB, const float2* __restrict__ alsB,
    const float2* __restrict__ aldB, const int* __restrict__ rowptrB,
    const int* __restrict__ colvB, const float2* __restrict__ alphB,
    P3f biasp, unsigned short* __restrict__ outB, int N, int E) {
  constexpr int HC = 2 * C;
  constexpr int FLd = HC / 8;       // active h lanes per slot: 16 (C=64) / 10 (C=40)
  constexpr int HB = C / 8;         // head boundary in lane units: 8 / 5
  constexpr int OW = CONCAT ? HC : C;
  const int o = blockIdx.y;
  const unsigned short* h = hB + (size_t)o * N * HC;
  const float2* al_s = alsB + (size_t)o * N;
  const float2* al_d = aldB + (size_t)o * N;
  const int* rowptr = rowptrB + o * (N + 1);
  const int* colv = colvB + (size_t)o * E;
  const float2* alph = alphB + (size_t)o * E;
  const float* bias = biasp.p[o];
  unsigned short* out = outB + (size_t)o * N * OW;

  const int gw = (blockIdx.x * blockDim.x + threadIdx.x) >> 6;
  const int lane = threadIdx.x & 63;
  const int slot = lane >> 4;
  const int f4 = lane & 15;
  const int w = gw * 4 + slot;
  if (gw * 4 >= N) return;
  const bool vn = w < N;
  const int wc = vn ? w : N - 1;
  const bool hl = f4 < FLd;

  const int beg = rowptr[wc];
  const int deg = vn ? (rowptr[wc + 1] - beg) : 0;
  int md = deg;
  md = max(md, __shfl_xor(md, 32, 64));
  md = max(md, __shfl_xor(md, 16, 64));   // wave-uniform max degree over 4 slots

  const float2 ad = al_d[wc];
  const float2 asf = al_s[wc];
  const float xs0 = __expf(leakyf(asf.x + ad.x));
  const float xs1 = __expf(leakyf(asf.y + ad.y));
  float dp0 = xs0, dp1 = xs1;

  f32x2 acc[4] = {}, acc2[4] = {};
  // self-loop message first (independent of edge loop)
  if (hl) {
    uint4 q = ((const uint4*)(h + (size_t)wc * HC))[f4];
    bf8_fma2(q, (f4 < HB) ? xs0 : xs1, acc);
  }

  const float2 z2 = make_float2(0.f, 0.f);
  for (int t = 0; t < md; t += 4) {
    const int j0 = beg + t;
    const bool v0 = t < deg;
    const bool v1 = t + 1 < deg;
    const bool v2 = t + 2 < deg;
    const bool v3 = t + 3 < deg;
    // guarded index/alpha loads: never OOB (invalid -> 0)
    const int s0 = v0 ? colv[j0] : 0;
    const int s1 = v1 ? colv[j0 + 1] : 0;
    const int s2 = v2 ? colv[j0 + 2] : 0;
    const int s3 = v3 ? colv[j0 + 3] : 0;
    const float2 a0 = v0 ? alph[j0] : z2;
    const float2 a1 = v1 ? alph[j0 + 1] : z2;
    const float2 a2 = v2 ? alph[j0 + 2] : z2;
    const float2 a3 = v3 ? alph[j0 + 3] : z2;
    // h gathers: exec-masked per slot (v[k] is slot-uniform)
    uint4 q0 = make_uint4(0, 0, 0, 0), q1 = q0, q2 = q0, q3 = q0;
    if (v0 && hl) q0 = ((const uint4*)(h + (size_t)s0 * HC))[f4];
    if (v1 && hl) q1 = ((const uint4*)(h + (size_t)s1 * HC))[f4];
    if (v2 && hl) q2 = ((const uint4*)(h + (size_t)s2 * HC))[f4];
    if (v3 && hl) q3 = ((const uint4*)(h + (size_t)s3 * HC))[f4];
    dp0 += (a0.x + a1.x) + (a2.x + a3.x);
    dp1 += (a0.y + a1.y) + (a2.y + a3.y);
    if (v0 && hl) bf8_fma2(q0, (f4 < HB) ? a0.x : a0.y, acc);
    if (v1 && hl) bf8_fma2(q1, (f4 < HB) ? a1.x : a1.y, acc2);
    if (v2 && hl) bf8_fma2(q2, (f4 < HB) ? a2.x : a2.y, acc);
    if (v3 && hl) bf8_fma2(q3, (f4 < HB) ? a3.x : a3.y, acc2);
  }
#pragma unroll
  for (int i = 0; i < 4; ++i) acc[i] += acc2[i];

  const float inv0 = 1.f / (dp0 + 1e-16f), inv1 = 1.f / (dp1 + 1e-16f);
  if (CONCAT) {
    if (vn && hl) {
      const float xx = (f4 < HB) ? inv0 : inv1;
      const float* bp = bias + f4 * 8;
      unsigned int pk[4];
#pragma unroll
      for (int i = 0; i < 4; ++i) {
        unsigned short lo = bf16r(eluf(acc[i][0] * xx + bp[2 * i]));
        unsigned short hi = bf16r(eluf(acc[i][1] * xx + bp[2 * i + 1]));
        pk[i] = (unsigned int)lo | ((unsigned int)hi << 16);
      }
      ((uint4*)(out + (size_t)w * OW + f4 * 8))[0] = make_uint4(pk[0], pk[1], pk[2], pk[3]);
    }
  } else {
    // mean over 2 heads: head-1 partials live at f4 in [HB, 2*HB) of same slot
    float p[8];
#pragma unroll
    for (int i = 0; i < 4; ++i) {
      p[2 * i]     = __shfl(acc[i][0], lane + HB, 64);
      p[2 * i + 1] = __shfl(acc[i][1], lane + HB, 64);
    }
    if (vn && f4 < HB) {
      const float* bp = bias + f4 * 8;
      unsigned int pk[4];
#pragma unroll
      for (int i = 0; i < 4; ++i) {
        float v0 = 0.5f * (acc[i][0] * inv0 + p[2 * i] * inv1) + bp[2 * i];
        float v1 = 0.5f * (acc[i][1] * inv0 + p[2 * i + 1] * inv1) + bp[2 * i + 1];
        pk[i] = (unsigned int)bf16r(eluf(v0)) | ((unsigned int)bf16r(eluf(v1)) << 16);
      }
      ((uint4*)(out + (size_t)w * OW + f4 * 8))[0] = make_uint4(pk[0], pk[1], pk[2], pk[3]);
    }
  }
}

// ---------------- order-mix (bf16 states in; bf16 out) — layer 0 ----------
template<int BF16OUT>
__global__ __launch_bounds__(256) void mixb_kernel(const unsigned short* __restrict__ sb,
    const float* __restrict__ Wm, const float* __restrict__ wf,
    void* __restrict__ out, int perU) {
  int i = blockIdx.x * blockDim.x + threadIdx.x;
  if (i >= perU) return;
  const unsigned int* sp = (const unsigned int*)sb;
  unsigned int u0 = sp[i];
  unsigned int u1 = sp[perU + i];
  unsigned int u2 = sp[2 * perU + i];
  float a0 = bflo(u0), a1 = bfhi(u0);
  float b0 = bflo(u1), b1 = bfhi(u1);
  float c0 = bflo(u2), c1 = bfhi(u2);
  float r0 = 0.f, r1 = 0.f;
#pragma unroll
  for (int j = 0; j < 3; ++j) {
    float w0 = Wm[j], w1 = Wm[3 + j], w2 = Wm[6 + j], wj = wf[j];
    r0 += wj * eluf(a0 * w0 + b0 * w1 + c0 * w2);
    r1 += wj * eluf(a1 * w0 + b1 * w1 + c1 * w2);
  }
  if (BF16OUT) {
    ((unsigned int*)out)[i] = (unsigned int)bf16r(r0) | ((unsigned int)bf16r(r1) << 16);
  } else {
    ((float2*)out)[i] = make_float2(r0, r1);
  }
}

// ---------------- fused layer-1 order-mix + log_softmax ---------------------
// One wave = 2 nodes: lanes 0-19 own node A's 20 channel-pairs, lanes 32-51
// own node B's. Mix computed in-register (same math as mixb<0>), then
// max/sum reductions within each 32-lane half, direct fp32 d_out write.
__global__ __launch_bounds__(256) void mixfin_kernel(const unsigned short* __restrict__ sb,
    const float* __restrict__ Wm, const float* __restrict__ wf,
    float* __restrict__ out, int N) {
  const int gw = (blockIdx.x * blockDim.x + threadIdx.x) >> 6;
  const int lane = threadIdx.x & 63;
  const int half = lane >> 5;           // 0 or 1 -> node gw*2+half
  const int hl = lane & 31;             // lane within half
  const int w = gw * 2 + half;
  if (gw * 2 >= N) return;
  const bool vn = w < N;
  const bool act = hl < 20;             // 20 channel-pairs per node (C1=40)
  const int perU = N * 20;
  const unsigned int* sp = (const unsigned int*)sb;

  float r0 = 0.f, r1 = 0.f;
  if (vn && act) {
    const size_t i = (size_t)w * 20 + hl;
    unsigned int u0 = sp[i];
    unsigned int u1 = sp[perU + i];
    unsigned int u2 = sp[2 * (size_t)perU + i];
    float a0 = bflo(u0), a1 = bfhi(u0);
    float b0 = bflo(u1), b1 = bfhi(u1);
    float c0 = bflo(u2), c1 = bfhi(u2);
#pragma unroll
    for (int j = 0; j < 3; ++j) {
      float w0 = Wm[j], w1 = Wm[3 + j], w2 = Wm[6 + j], wj = wf[j];
      r0 += wj * eluf(a0 * w0 + b0 * w1 + c0 * w2);
      r1 += wj * eluf(a1 * w0 + b1 * w1 + c1 * w2);
    }
  }
  // log-softmax over the 40 values held by this half's 20 active lanes
  float mx = (vn && act) ? fmaxf(r0, r1) : -INFINITY;
#pragma unroll
  for (int off = 1; off < 32; off <<= 1) mx = fmaxf(mx, __shfl_xor(mx, off, 32));
  float ex = (vn && act) ? (expf(r0 - mx) + expf(r1 - mx)) : 0.f;
#pragma unroll
  for (int off = 1; off < 32; off <<= 1) ex += __shfl_xor(ex, off, 32);
  if (vn && act) {
    const float ls = logf(ex);
    ((float2*)(out + (size_t)w * 40))[hl] = make_float2(r0 - mx - ls, r1 - mx - ls);
  }
}

// ---------------------------------------------------------------------------
extern "C" void kernel_launch(void* const* d_in, const int* in_sizes, int n_in,
                              void* d_out, int out_size, void* d_ws, size_t ws_size,
                              hipStream_t stream) {
  const int F_IN = 500;
  const int N = in_sizes[0] / F_IN;     // 50000
  const int E = in_sizes[1] / 2;        // 800000
  const int HC0 = 128;
  const int HC1 = 80;
  const int C1 = 40;
  const int K0pad = 512, K1pad = 128;

  const float* x0 = (const float*)d_in[0];
  P3c adj;
  adj.p[0] = (const int*)d_in[1];
  adj.p[1] = (const int*)d_in[2];
  adj.p[2] = (const int*)d_in[3];
  P3f W0p, as0p, ad0p, b0p, W1p, as1p, ad1p, b1p;
  for (int o = 0; o < 3; ++o) {
    W0p.p[o]  = (const float*)d_in[4 + 4 * o + 0];
    as0p.p[o] = (const float*)d_in[4 + 4 * o + 1];
    ad0p.p[o] = (const float*)d_in[4 + 4 * o + 2];
    b0p.p[o]  = (const float*)d_in[4 + 4 * o + 3];
    W1p.p[o]  = (const float*)d_in[16 + 4 * o + 0];
    as1p.p[o] = (const float*)d_in[16 + 4 * o + 1];
    ad1p.p[o] = (const float*)d_in[16 + 4 * o + 2];
    b1p.p[o]  = (const float*)d_in[16 + 4 * o + 3];
  }
  const float* agg0W = (const float*)d_in[28];
  const float* agg0w = (const float*)d_in[29];
  const float* agg1W = (const float*)d_in[30];
  const float* agg1w = (const float*)d_in[31];

  // ---- workspace layout ----
  char* ws = (char*)d_ws;
  size_t off = 0;
  auto alloc = [&](size_t bytes) -> void* {
    off = (off + 255) & ~(size_t)255;
    void* p = ws + off;
    off += bytes;
    return p;
  };
  int* rowptrb = (int*)alloc((size_t)3 * (N + 1) * 4);
  int* colvb   = (int*)alloc((size_t)3 * E * 4);
  int* cntb    = (int*)alloc((size_t)3 * N * 4);
  int* bsums   = (int*)alloc(3 * 64 * 4);
  unsigned short* x0b = (unsigned short*)alloc((size_t)N * K0pad * 2);    // bf16 x0
  unsigned short* hB  = (unsigned short*)alloc((size_t)3 * N * HC0 * 2);  // bf16 h
  unsigned short* stB = (unsigned short*)alloc((size_t)3 * N * HC0 * 2);  // bf16 states; block0 reused as bf16 x1
  float2* alsB = (float2*)alloc((size_t)3 * N * 8);
  float2* aldB = (float2*)alloc((size_t)3 * N * 8);
  unsigned short* Bt0B = (unsigned short*)alloc((size_t)3 * HC0 * K0pad * 2);
  unsigned short* Bt1B = (unsigned short*)alloc((size_t)3 * HC1 * K1pad * 2);
  // Aliases (all rewritten before first read on every run, in stream order):
  //  - alphb (19.2MB) aliases x0b (51.2MB): x0b dead after fused GEMM L0;
  //    alpha3 runs after it.
  //  - posb (9.6MB) aliases stB (38.4MB): fused kernel writes posb (count
  //    path) + hB (GEMM path) -> posb must NOT alias hB. stB is first
  //    written by gat L0, which runs after fill3 consumed posb.
  float2* alphb = (float2*)x0b;
  int* posb = (int*)stB;
  (void)ws_size;

  const int TB = 256;
  const int nbE = (E + TB - 1) / TB;
  const int nbN = (N + TB - 1) / TB;
  const int scanBlocks = (N + SCAN_TILE - 1) / SCAN_TILE;
  const int gemmBlocks = (N + GBM - 1) / GBM;
  const int slot4Blocks = (int)(((size_t)((N + 3) / 4) * 64 + TB - 1) / TB);
  const int finBlocks = (int)(((size_t)((N + 1) / 2) * 64 + TB - 1) / TB);

  // ---- conversions ----
  convA_kernel<<<(int)(((size_t)N * 64 + TB - 1) / TB), TB, 0, stream>>>(
      x0, x0b, N, F_IN, K0pad);
  conv_bt3_kernel<<<dim3((K0pad + 255) / 256, HC0, 3), TB, 0, stream>>>(W0p, Bt0B, F_IN, HC0, K0pad);
  conv_bt3_kernel<<<dim3((K1pad + 255) / 256, HC1, 3), TB, 0, stream>>>(W1p, Bt1B, HC0, HC1, K1pad);

  // ---- fused GEMM L0 + edge count (independent work, co-scheduled) ----
  zero_int_kernel<<<(3 * N + TB - 1) / TB, TB, 0, stream>>>(cntb, 3 * N);
  if (8 * gemmBlocks >= nbE) {
    gemm0_count_kernel<<<dim3(gemmBlocks * 9, 3), TB, 0, stream>>>(
        x0b, Bt0B, as0p, ad0p, hB, alsB, aldB, N, K0pad,
        adj, cntb, posb, E, N, gemmBlocks);
  } else {  // size fallback: sequential (correctness-preserving)
    count3_kernel<<<dim3(nbE, 3), TB, 0, stream>>>(adj, cntb, posb, E, N);
    mfma_gemm_kernel<8><<<dim3(gemmBlocks, 3), TB, 0, stream>>>(
        x0b, Bt0B, as0p, ad0p, hB, alsB, aldB, N, K0pad);
  }

  // ---- CSR finalize ----
  scan1_kernel<<<dim3(scanBlocks, 3), SCAN_T, 0, stream>>>(cntb, rowptrb, bsums, N);
  scan2_kernel<<<1, 64, 0, stream>>>(bsums, scanBlocks, rowptrb, N);
  scan3_kernel<<<dim3(nbN, 3), TB, 0, stream>>>(rowptrb, bsums, N);
  fill3_kernel<<<dim3(nbE, 3), TB, 0, stream>>>(adj, rowptrb, posb, colvb, E, N);

  // ---- layer 0 (concat) ----
  alpha3_kernel<<<dim3(nbN, 3), TB, 0, stream>>>(rowptrb, colvb, alsB, aldB, alphb, N, E);
  gat_slot4_kernel<64, 1><<<dim3(slot4Blocks, 3), TB, 0, stream>>>(
      hB, alsB, aldB, rowptrb, colvb, alphb, b0p, stB, N, E);
  mixb_kernel<1><<<((N * HC0 / 2) + TB - 1) / TB, TB, 0, stream>>>(
      stB, agg0W, agg0w, stB, N * HC0 / 2);   // in-place bf16 x1 over state block 0

  // ---- layer 1 (mean over heads) ----
  mfma_gemm_kernel<5><<<dim3(gemmBlocks, 3), TB, 0, stream>>>(
      stB, Bt1B, as1p, ad1p, hB, alsB, aldB, N, K1pad);
  alpha3_kernel<<<dim3(nbN, 3), TB, 0, stream>>>(rowptrb, colvb, alsB, aldB, alphb, N, E);
  gat_slot4_kernel<40, 0><<<dim3(slot4Blocks, 3), TB, 0, stream>>>(
      hB, alsB, aldB, rowptrb, colvb, alphb, b1p, stB, N, E);
  // fused order-mix + log_softmax (replaces mixb<0> + log_softmax)
  mixfin_kernel<<<finBlocks, TB, 0, stream>>>(stB, agg1W, agg1w, (float*)d_out, N);
}